// Round 4
// baseline (1827.242 us; speedup 1.0000x reference)
//
#include <hip/hip_runtime.h>
#include <math.h>

#define N_NODES 20000
#define N_EDGES 320000
#define N_GRAPHS 64
#define PD 9
#define KD 32
#define MD 32
#define NK 5
#define EIN 161
#define EIN2 322
#define ALLF (KD*(NK+1))   // 192
#define LN_EPS 1e-5f

typedef __attribute__((ext_vector_type(8))) short short8;
typedef __attribute__((ext_vector_type(4))) float f32x4;
typedef __attribute__((ext_vector_type(4))) unsigned u32x4;
typedef __attribute__((ext_vector_type(2))) unsigned u32x2;
typedef __attribute__((ext_vector_type(4))) int i32x4;

__device__ __forceinline__ float silu_f(float x) { return x / (1.f + __expf(-x)); }

__device__ __forceinline__ unsigned short f2bf(float x) {
    union { float f; unsigned u; } v; v.f = x;
    unsigned r = v.u + 0x7FFFu + ((v.u >> 16) & 1u);
    return (unsigned short)(r >> 16);
}

__device__ __forceinline__ unsigned cvt_pk_bf16(float lo, float hi) {
    unsigned r;
    asm("v_cvt_pk_bf16_f32 %0, %1, %2" : "=v"(r) : "v"(lo), "v"(hi));
    return r;
}

// ---------------- weight packing: W1 -> bf16 MFMA A/B-frag order ----------------
// packed K (160): 0-31 feats_dst, 32-63 feats_src, 64-95 sin, 96-127 cos,
// 128-159 edge_feats (orig rows 129..160). Orig row 128 (rel_dist) is a rank-1
// epilogue update. Layout: [k][nt(21)][kb(5)][lane(64)][i(8)]
__global__ __launch_bounds__(256) void pack_w1_kernel(
    const float* __restrict__ eW1, unsigned short* __restrict__ W1p)
{
    int fid = blockIdx.x * 256 + threadIdx.x;
    if (fid >= NK*21*5*64) return;
    int kk = fid / (21*5*64);
    int r  = fid % (21*5*64);
    int nt = r / (5*64);
    int r2 = r % (5*64);
    int kb = r2 >> 6;
    int l  = r2 & 63;
    int q = l >> 4, el = l & 15;
    int n = 16*nt + el;
    short8 out;
    #pragma unroll
    for (int i = 0; i < 8; ++i) {
        int kp = 32*kb + 8*q + i;
        int orig = (kp < 128) ? kp : kp + 1; // skip rel_dist row 128
        float v = (n < EIN2) ? eW1[((size_t)kk*EIN + orig)*EIN2 + n] : 0.f;
        out[i] = (short)f2bf(v);
    }
    *(short8*)&W1p[(size_t)fid*8] = out;
}

// W2 packed: K2 = 352 (11 kb blocks; rows >=322 zero). [k][nt2(2)][kb2(11)][lane][i]
__global__ __launch_bounds__(256) void pack_w2_kernel(
    const float* __restrict__ eW2, unsigned short* __restrict__ W2p)
{
    int fid = blockIdx.x * 256 + threadIdx.x;
    if (fid >= NK*2*11*64) return;
    int kk = fid / (2*11*64);
    int r  = fid % (2*11*64);
    int nt2 = r / (11*64);
    int r2  = r % (11*64);
    int kb2 = r2 >> 6;
    int l   = r2 & 63;
    int q = l >> 4, el = l & 15;
    int n = 16*nt2 + el;
    short8 out;
    #pragma unroll
    for (int i = 0; i < 8; ++i) {
        int k2 = 32*kb2 + 8*q + i;
        float v = (k2 < EIN2) ? eW2[((size_t)kk*EIN2 + k2)*MD + n] : 0.f;
        out[i] = (short)f2bf(v);
    }
    *(short8*)&W2p[(size_t)fid*8] = out;
}

// node weights: W1A [kk][mt(4)][kb(2)][lane][8]; W2A [kk][mt2(2)][kb(2)][lane][8]
__global__ __launch_bounds__(256) void pack_nw_kernel(
    const float* __restrict__ nW1, const float* __restrict__ nW2,
    unsigned short* __restrict__ W1A, unsigned short* __restrict__ W2A)
{
    int fid = blockIdx.x * 256 + threadIdx.x;
    const int tot1 = NK*4*2*64;
    const int tot2 = NK*2*2*64;
    if (fid < tot1) {
        int kk = fid / (4*2*64);
        int r  = fid % (4*2*64);
        int mt = r / 128;
        int r2 = r % 128;
        int kb = r2 >> 6;
        int l  = r2 & 63;
        int q = l >> 4, el = l & 15;
        short8 out;
        #pragma unroll
        for (int i = 0; i < 8; ++i)
            out[i] = (short)f2bf(nW1[((size_t)kk*64 + 32*kb + 8*q + i)*64 + 16*mt + el]);
        *(short8*)&W1A[(size_t)fid*8] = out;
    } else if (fid < tot1 + tot2) {
        int f2 = fid - tot1;
        int kk = f2 / (2*2*64);
        int r  = f2 % (2*2*64);
        int mt2 = r / 128;
        int r2  = r % 128;
        int kb  = r2 >> 6;
        int l   = r2 & 63;
        int q = l >> 4, el = l & 15;
        short8 out;
        #pragma unroll
        for (int i = 0; i < 8; ++i)
            out[i] = (short)f2bf(nW2[((size_t)kk*64 + 32*kb + 8*q + i)*32 + 16*mt2 + el]);
        *(short8*)&W2A[(size_t)f2*8] = out;
    }
}

// ---------------- node embed + pooled sum slot 0 ----------------
__global__ __launch_bounds__(256) void embed_nodes_kernel(
    const float* __restrict__ props, const float* __restrict__ W,
    const float* __restrict__ b, const int* __restrict__ batch,
    float* __restrict__ feats, unsigned short* __restrict__ feats_bf,
    float* __restrict__ gsum, float* __restrict__ gcnt)
{
    int t = threadIdx.x;
    int n = blockIdx.x * 8 + (t >> 5);
    int f = t & 31;
    if (n >= N_NODES) return;
    float acc = b[f];
    #pragma unroll
    for (int i = 0; i < PD; ++i) acc += props[n*PD + i] * W[i*KD + f];
    feats[n*KD + f] = acc;
    feats_bf[n*KD + f] = f2bf(acc);
    int g = batch[n];
    atomicAdd(&gsum[g*ALLF + f], acc);
    if (f == 0) atomicAdd(&gcnt[g], 1.f);
}

// ------- edge prep (fused): edge embed + rel_dist + deg + constpack -------
// constpack per 64-edge block b: [w(4)][kbr(3: sin,cos,ef)][lane(64)][i(8)] bf16
__global__ __launch_bounds__(256) void edge_prep_kernel(
    const float* __restrict__ edge_props, const float* __restrict__ positions,
    const int* __restrict__ ei, const float* __restrict__ W,
    const float* __restrict__ b, float* __restrict__ rel,
    float* __restrict__ deg, unsigned short* __restrict__ constpack)
{
    __shared__ float ef[64*32];
    __shared__ float rdl[64];
    int t = threadIdx.x;
    int b0 = blockIdx.x;
    int e0 = b0 * 64;

    {
        int e = t >> 2, sub = t & 3;
        float acc[8];
        #pragma unroll
        for (int j = 0; j < 8; ++j) acc[j] = b[sub*8 + j];
        #pragma unroll
        for (int i = 0; i < PD; ++i) {
            float p = edge_props[(size_t)(e0 + e)*PD + i];
            #pragma unroll
            for (int j = 0; j < 8; ++j) acc[j] += p * W[i*KD + sub*8 + j];
        }
        #pragma unroll
        for (int j = 0; j < 8; ++j) ef[e*32 + sub*8 + j] = acc[j];
    }
    if (t < 64) {
        int e = e0 + t;
        int s = ei[e], d = ei[N_EDGES + e];
        float dx = positions[s*3+0] - positions[d*3+0];
        float dy = positions[s*3+1] - positions[d*3+1];
        float dz = positions[s*3+2] - positions[d*3+2];
        float rd = dx*dx + dy*dy + dz*dz;
        rdl[t] = rd;
        rel[e] = rd;
        atomicAdd(&deg[d], 1.f);
    }
    __syncthreads();

    int l = t & 63, w = t >> 6;
    int q = l >> 4, el = l & 15;
    float rd = rdl[16*w + el];
    #pragma unroll
    for (int kbr = 0; kbr < 3; ++kbr) {
        short8 out;
        #pragma unroll
        for (int i = 0; i < 8; ++i) {
            int k = 8*q + i;
            float v;
            if (kbr == 0)      v = sinf(ldexpf(rd, -k));
            else if (kbr == 1) v = cosf(ldexpf(rd, -k));
            else               v = ef[(16*w + el)*32 + k];
            out[i] = (short)f2bf(v);
        }
        *(short8*)&constpack[((((size_t)b0*4 + w)*3 + kbr)*64 + l)*8] = out;
    }
}

// ---------------- MFMA edge MLP (swapped GEMM1, register exchange) ----------------
// 64 edges/block, 4 waves x 16 edges. No LDS, no barriers.
// GEMM1: acc = mfma(W1frag, hfrag) -> lane holds n1=16nt+4q+j for ITS edge el.
// silu -> cvt_pk -> 4x shfl redistributes to GEMM2 A-frag in registers.
__global__ __launch_bounds__(256) void edge_mlp_mfma(
    const unsigned short* __restrict__ feats_bf,
    const unsigned short* __restrict__ constpack,
    const float* __restrict__ rel, const int* __restrict__ ei,
    const unsigned short* __restrict__ W1p, const unsigned short* __restrict__ W2p,
    const float* __restrict__ w1rd, const float* __restrict__ eb1,
    const float* __restrict__ eb2, const float* __restrict__ lg,
    const float* __restrict__ lb, float* __restrict__ msum)
{
    int t = threadIdx.x;
    int b = blockIdx.x;
    int w = t >> 6, l = t & 63, q = l >> 4, el = l & 15;
    int e0 = b * 64;
    int eMine = e0 + 16*w + el;
    int srcn = ei[eMine];
    int dstn = ei[N_EDGES + eMine];
    float rd = rel[eMine];

    short8 a0 = *(const short8*)&feats_bf[(size_t)dstn*KD + 8*q];
    short8 a1 = *(const short8*)&feats_bf[(size_t)srcn*KD + 8*q];
    const unsigned short* cp = &constpack[((size_t)(b*4 + w)*3)*512 + (size_t)l*8];
    short8 a2 = *(const short8*)&cp[0];
    short8 a3 = *(const short8*)&cp[512];
    short8 a4 = *(const short8*)&cp[1024];

    unsigned h1r[44];
    #pragma unroll
    for (int i = 0; i < 44; ++i) h1r[i] = 0u;

    const int sA = 32*(q & 1) + el;   // exchange source lanes
    const int sB = sA + 16;
    const int myp = q >> 1;           // parity this lane consumes

    #pragma unroll
    for (int nt = 0; nt < 21; ++nt) {
        f32x4 acc = {0.f, 0.f, 0.f, 0.f};
        const unsigned short* wb = &W1p[(size_t)(nt*5)*512 + (size_t)l*8];
        acc = __builtin_amdgcn_mfma_f32_16x16x32_bf16(*(const short8*)&wb[0],    a0, acc, 0, 0, 0);
        acc = __builtin_amdgcn_mfma_f32_16x16x32_bf16(*(const short8*)&wb[512],  a1, acc, 0, 0, 0);
        acc = __builtin_amdgcn_mfma_f32_16x16x32_bf16(*(const short8*)&wb[1024], a2, acc, 0, 0, 0);
        acc = __builtin_amdgcn_mfma_f32_16x16x32_bf16(*(const short8*)&wb[1536], a3, acc, 0, 0, 0);
        acc = __builtin_amdgcn_mfma_f32_16x16x32_bf16(*(const short8*)&wb[2048], a4, acc, 0, 0, 0);

        float vj[4];
        if (nt < 20) {
            f32x4 be = *(const f32x4*)&eb1[16*nt + 4*q];
            f32x4 wr = *(const f32x4*)&w1rd[16*nt + 4*q];
            #pragma unroll
            for (int j = 0; j < 4; ++j)
                vj[j] = silu_f(acc[j] + be[j] + rd * wr[j]);
        } else {
            int nb = 320 + 4*q;
            #pragma unroll
            for (int j = 0; j < 4; ++j) {
                int n1 = nb + j;
                bool ok = n1 < EIN2;
                float be = ok ? eb1[n1] : 0.f;
                float wr = ok ? w1rd[n1] : 0.f;
                float v = silu_f(acc[j] + be + rd * wr);
                vj[j] = ok ? v : 0.f;
            }
        }

        unsigned P0 = cvt_pk_bf16(vj[0], vj[1]);
        unsigned P1 = cvt_pk_bf16(vj[2], vj[3]);
        unsigned g0 = (unsigned)__shfl((int)P0, sA);
        unsigned g1 = (unsigned)__shfl((int)P1, sA);
        unsigned g2 = (unsigned)__shfl((int)P0, sB);
        unsigned g3 = (unsigned)__shfl((int)P1, sB);
        const int kb2 = nt >> 1;
        bool recv = (myp == (nt & 1));
        h1r[kb2*4+0] = recv ? g0 : h1r[kb2*4+0];
        h1r[kb2*4+1] = recv ? g1 : h1r[kb2*4+1];
        h1r[kb2*4+2] = recv ? g2 : h1r[kb2*4+2];
        h1r[kb2*4+3] = recv ? g3 : h1r[kb2*4+3];
    }

    // GEMM2: A = h1 (register frags), B = W2p. K=352, N=32.
    f32x4 acc20 = {0.f, 0.f, 0.f, 0.f};
    f32x4 acc21 = {0.f, 0.f, 0.f, 0.f};
    #pragma unroll
    for (int kb2 = 0; kb2 < 11; ++kb2) {
        u32x4 hv = { h1r[kb2*4+0], h1r[kb2*4+1], h1r[kb2*4+2], h1r[kb2*4+3] };
        short8 av = __builtin_bit_cast(short8, hv);
        short8 b0 = *(const short8*)&W2p[(size_t)kb2*512 + (size_t)l*8];
        short8 b1 = *(const short8*)&W2p[(size_t)(11 + kb2)*512 + (size_t)l*8];
        acc20 = __builtin_amdgcn_mfma_f32_16x16x32_bf16(av, b0, acc20, 0, 0, 0);
        acc21 = __builtin_amdgcn_mfma_f32_16x16x32_bf16(av, b1, acc21, 0, 0, 0);
    }

    // epilogue: silu -> per-edge LayerNorm (32 cols) -> atomic aggregate.
    // lane (q,el): edge 16w+4q+j (row), cols el and 16+el.
    i32x4 dstv = *(const i32x4*)&ei[N_EDGES + e0 + 16*w + 4*q];
    float e20 = eb2[el], e21 = eb2[16 + el];
    float g0v = lg[el],  g1v = lg[16 + el];
    float b0v = lb[el],  b1v = lb[16 + el];
    #pragma unroll
    for (int j = 0; j < 4; ++j) {
        float m0 = silu_f(acc20[j] + e20);
        float m1 = silu_f(acc21[j] + e21);
        float s = m0 + m1;
        s += __shfl_xor(s, 1, 16); s += __shfl_xor(s, 2, 16);
        s += __shfl_xor(s, 4, 16); s += __shfl_xor(s, 8, 16);
        float mu = s * (1.f/32.f);
        float d0 = m0 - mu, d1 = m1 - mu;
        float vv = d0*d0 + d1*d1;
        vv += __shfl_xor(vv, 1, 16); vv += __shfl_xor(vv, 2, 16);
        vv += __shfl_xor(vv, 4, 16); vv += __shfl_xor(vv, 8, 16);
        float rs = rsqrtf(vv * (1.f/32.f) + LN_EPS);
        int dst = dstv[j];
        atomicAdd(&msum[(size_t)dst*MD + el],      d0*rs*g0v + b0v);
        atomicAdd(&msum[(size_t)dst*MD + 16 + el], d1*rs*g1v + b1v);
    }
}

// ---------------- MFMA node MLP: 64 nodes/block, 16/wave ----------------
__global__ __launch_bounds__(256) void node_mlp_mfma(
    const float* __restrict__ msum, const float* __restrict__ deg,
    const unsigned short* __restrict__ W1A, const unsigned short* __restrict__ W2A,
    const float* __restrict__ nb1, const float* __restrict__ nb2,
    const float* __restrict__ eln_g, const float* __restrict__ eln_b,
    const float* __restrict__ n1g, const float* __restrict__ n1b,
    const float* __restrict__ n2g, const float* __restrict__ n2b,
    const int* __restrict__ batch,
    float* __restrict__ feats, unsigned short* __restrict__ feats_bf,
    float* __restrict__ gsum, int kslot)
{
    int t = threadIdx.x;
    int w = t >> 6, l = t & 63, q = l >> 4, el = l & 15;
    int nd = blockIdx.x*64 + 16*w + el;
    bool okn = nd < N_NODES;
    size_t ndc = okn ? (size_t)nd : (size_t)(N_NODES - 1);

    // ---- load input, dual group-LN, pack to B-frags ----
    float x[2][8];
    {
        f32x4 f0 = *(const f32x4*)&feats[ndc*KD + 8*q];
        f32x4 f1 = *(const f32x4*)&feats[ndc*KD + 8*q + 4];
        float inv = 1.f / fmaxf(deg[ndc], 1.f);
        f32x4 m0 = *(const f32x4*)&msum[ndc*KD + 8*q];
        f32x4 m1 = *(const f32x4*)&msum[ndc*KD + 8*q + 4];
        #pragma unroll
        for (int j = 0; j < 4; ++j) {
            x[0][j] = f0[j]; x[0][4+j] = f1[j];
            x[1][j] = m0[j]*inv; x[1][4+j] = m1[j]*inv;
        }
    }
    short8 xf[2];
    #pragma unroll
    for (int kb = 0; kb < 2; ++kb) {
        float s = 0.f;
        #pragma unroll
        for (int i = 0; i < 8; ++i) s += x[kb][i];
        s += __shfl_xor(s, 16); s += __shfl_xor(s, 32);
        float mu = s * (1.f/32.f);
        float vv = 0.f;
        #pragma unroll
        for (int i = 0; i < 8; ++i) { float d = x[kb][i] - mu; vv += d*d; }
        vv += __shfl_xor(vv, 16); vv += __shfl_xor(vv, 32);
        float rs = rsqrtf(vv * (1.f/32.f) + LN_EPS);
        const float* gp = kb ? eln_g : n1g;
        const float* bp = kb ? eln_b : n1b;
        f32x4 ga = *(const f32x4*)&gp[8*q];
        f32x4 gb = *(const f32x4*)&gp[8*q + 4];
        f32x4 ba = *(const f32x4*)&bp[8*q];
        f32x4 bb = *(const f32x4*)&bp[8*q + 4];
        float z[8];
        #pragma unroll
        for (int j = 0; j < 4; ++j) {
            z[j]   = (x[kb][j]   - mu)*rs*ga[j] + ba[j];
            z[4+j] = (x[kb][4+j] - mu)*rs*gb[j] + bb[j];
        }
        u32x4 pv = { cvt_pk_bf16(z[0], z[1]), cvt_pk_bf16(z[2], z[3]),
                     cvt_pk_bf16(z[4], z[5]), cvt_pk_bf16(z[6], z[7]) };
        xf[kb] = __builtin_bit_cast(short8, pv);
    }

    // ---- stage 1: h = silu(x @ W1 + b1), swapped MFMA + exchange ----
    const int sA = 32*(q & 1) + el;
    const int sB = sA + 16;
    const int myp = q >> 1;
    unsigned hr[8];
    #pragma unroll
    for (int i = 0; i < 8; ++i) hr[i] = 0u;

    #pragma unroll
    for (int mt = 0; mt < 4; ++mt) {
        f32x4 acc = {0.f, 0.f, 0.f, 0.f};
        acc = __builtin_amdgcn_mfma_f32_16x16x32_bf16(
            *(const short8*)&W1A[(size_t)(mt*2 + 0)*512 + (size_t)l*8], xf[0], acc, 0, 0, 0);
        acc = __builtin_amdgcn_mfma_f32_16x16x32_bf16(
            *(const short8*)&W1A[(size_t)(mt*2 + 1)*512 + (size_t)l*8], xf[1], acc, 0, 0, 0);
        f32x4 b1v = *(const f32x4*)&nb1[16*mt + 4*q];
        float vj[4];
        #pragma unroll
        for (int j = 0; j < 4; ++j) vj[j] = silu_f(acc[j] + b1v[j]);
        unsigned P0 = cvt_pk_bf16(vj[0], vj[1]);
        unsigned P1 = cvt_pk_bf16(vj[2], vj[3]);
        unsigned g0 = (unsigned)__shfl((int)P0, sA);
        unsigned g1 = (unsigned)__shfl((int)P1, sA);
        unsigned g2 = (unsigned)__shfl((int)P0, sB);
        unsigned g3 = (unsigned)__shfl((int)P1, sB);
        const int kb2 = mt >> 1;
        bool recv = (myp == (mt & 1));
        hr[kb2*4+0] = recv ? g0 : hr[kb2*4+0];
        hr[kb2*4+1] = recv ? g1 : hr[kb2*4+1];
        hr[kb2*4+2] = recv ? g2 : hr[kb2*4+2];
        hr[kb2*4+3] = recv ? g3 : hr[kb2*4+3];
    }

    // ---- stage 2: out = h @ W2 + b2 (swapped), then LN2 + residual ----
    u32x4 h0v = { hr[0], hr[1], hr[2], hr[3] };
    u32x4 h1v = { hr[4], hr[5], hr[6], hr[7] };
    short8 hf0 = __builtin_bit_cast(short8, h0v);
    short8 hf1 = __builtin_bit_cast(short8, h1v);
    float o[2][4];
    #pragma unroll
    for (int mt2 = 0; mt2 < 2; ++mt2) {
        f32x4 acc = {0.f, 0.f, 0.f, 0.f};
        acc = __builtin_amdgcn_mfma_f32_16x16x32_bf16(
            *(const short8*)&W2A[(size_t)(mt2*2 + 0)*512 + (size_t)l*8], hf0, acc, 0, 0, 0);
        acc = __builtin_amdgcn_mfma_f32_16x16x32_bf16(
            *(const short8*)&W2A[(size_t)(mt2*2 + 1)*512 + (size_t)l*8], hf1, acc, 0, 0, 0);
        f32x4 b2v = *(const f32x4*)&nb2[16*mt2 + 4*q];
        #pragma unroll
        for (int j = 0; j < 4; ++j) o[mt2][j] = acc[j] + b2v[j];
    }
    float s2 = 0.f;
    #pragma unroll
    for (int mt2 = 0; mt2 < 2; ++mt2)
        #pragma unroll
        for (int j = 0; j < 4; ++j) s2 += o[mt2][j];
    s2 += __shfl_xor(s2, 16); s2 += __shfl_xor(s2, 32);
    float mu2 = s2 * (1.f/32.f);
    float vv2 = 0.f;
    #pragma unroll
    for (int mt2 = 0; mt2 < 2; ++mt2)
        #pragma unroll
        for (int j = 0; j < 4; ++j) { float d = o[mt2][j] - mu2; vv2 += d*d; }
    vv2 += __shfl_xor(vv2, 16); vv2 += __shfl_xor(vv2, 32);
    float rs2 = rsqrtf(vv2 * (1.f/32.f) + LN_EPS);

    int gb = batch[ndc];
    #pragma unroll
    for (int mt2 = 0; mt2 < 2; ++mt2) {
        f32x4 gv = *(const f32x4*)&n2g[16*mt2 + 4*q];
        f32x4 bv = *(const f32x4*)&n2b[16*mt2 + 4*q];
        f32x4 fold = *(const f32x4*)&feats[ndc*KD + 16*mt2 + 4*q];
        f32x4 nf;
        #pragma unroll
        for (int j = 0; j < 4; ++j)
            nf[j] = fold[j] + (o[mt2][j] - mu2)*rs2*gv[j] + bv[j];
        if (okn) {
            *(f32x4*)&feats[(size_t)nd*KD + 16*mt2 + 4*q] = nf;
            u32x2 pb = { cvt_pk_bf16(nf[0], nf[1]), cvt_pk_bf16(nf[2], nf[3]) };
            *(u32x2*)&feats_bf[(size_t)nd*KD + 16*mt2 + 4*q] = pb;
            #pragma unroll
            for (int j = 0; j < 4; ++j)
                atomicAdd(&gsum[(size_t)gb*ALLF + kslot*KD + 16*mt2 + 4*q + j], nf[j]);
        }
    }
}

// ---------------- final FNN: block per graph ----------------
__global__ __launch_bounds__(256) void fnn_kernel(
    const float* __restrict__ gsum, const float* __restrict__ gcnt,
    const float* __restrict__ W0, const float* __restrict__ b0,
    const float* __restrict__ W1, const float* __restrict__ b1,
    const float* __restrict__ W2, const float* __restrict__ b2,
    const float* __restrict__ W3, const float* __restrict__ b3,
    float* __restrict__ out)
{
    __shared__ float xs[256];
    __shared__ float partial[4];
    int g = blockIdx.x, t = threadIdx.x;
    float inv = 1.f / fmaxf(gcnt[g], 1.f);
    if (t < ALLF) xs[t] = gsum[g*ALLF + t] * inv;
    __syncthreads();
    float acc = b0[t];
    for (int i = 0; i < ALLF; ++i) acc += xs[i] * W0[i*256 + t];
    acc = silu_f(acc);
    __syncthreads(); xs[t] = acc; __syncthreads();
    acc = b1[t];
    for (int i = 0; i < 256; ++i) acc += xs[i] * W1[i*256 + t];
    acc = silu_f(acc);
    __syncthreads(); xs[t] = acc; __syncthreads();
    acc = b2[t];
    for (int i = 0; i < 256; ++i) acc += xs[i] * W2[i*256 + t];
    acc = silu_f(acc);
    __syncthreads(); xs[t] = acc; __syncthreads();
    float v = xs[t] * W3[t];
    #pragma unroll
    for (int m = 32; m; m >>= 1) v += __shfl_xor(v, m, 64);
    if ((t & 63) == 0) partial[t >> 6] = v;
    __syncthreads();
    if (t == 0) out[g] = partial[0] + partial[1] + partial[2] + partial[3] + b3[0];
}

extern "C" void kernel_launch(void* const* d_in, const int* in_sizes, int n_in,
                              void* d_out, int out_size, void* d_ws, size_t ws_size,
                              hipStream_t stream) {
    const float* props      = (const float*)d_in[0];
    const float* positions  = (const float*)d_in[1];
    const float* edge_props = (const float*)d_in[2];
    const float* embed_W    = (const float*)d_in[3];
    const float* embed_b    = (const float*)d_in[4];
    const float* eeW        = (const float*)d_in[5];
    const float* eeb        = (const float*)d_in[6];
    const float* k_eW1      = (const float*)d_in[7];
    const float* k_eb1      = (const float*)d_in[8];
    const float* k_eW2      = (const float*)d_in[9];
    const float* k_eb2      = (const float*)d_in[10];
    const float* k_eln_g    = (const float*)d_in[11];
    const float* k_eln_b    = (const float*)d_in[12];
    const float* k_n1g      = (const float*)d_in[13];
    const float* k_n1b      = (const float*)d_in[14];
    const float* k_n2g      = (const float*)d_in[15];
    const float* k_n2b      = (const float*)d_in[16];
    const float* k_nW1      = (const float*)d_in[17];
    const float* k_nb1      = (const float*)d_in[18];
    const float* k_nW2      = (const float*)d_in[19];
    const float* k_nb2      = (const float*)d_in[20];
    const float* fnn_W0     = (const float*)d_in[21];
    const float* fnn_b0     = (const float*)d_in[22];
    const float* fnn_W1     = (const float*)d_in[23];
    const float* fnn_b1     = (const float*)d_in[24];
    const float* fnn_W2     = (const float*)d_in[25];
    const float* fnn_b2     = (const float*)d_in[26];
    const float* fnn_W3     = (const float*)d_in[27];
    const float* fnn_b3     = (const float*)d_in[28];
    const int*   ei         = (const int*)d_in[29];
    const int*   batch      = (const int*)d_in[30];
    float* out = (float*)d_out;

    // ---- workspace layout (bytes, 256-aligned) ----
    char* wsb = (char*)d_ws;
    size_t off = 0;
    #define WS_ALLOC(ptr_t, name, bytes) ptr_t name = (ptr_t)(wsb + off); off += (((size_t)(bytes)) + 255) & ~(size_t)255;
    WS_ALLOC(float*, feats, (size_t)N_NODES*KD*4)
    WS_ALLOC(float*, msum,  (size_t)N_NODES*KD*4)
    WS_ALLOC(float*, deg,   (size_t)N_NODES*4)
    WS_ALLOC(float*, rel,   (size_t)N_EDGES*4)
    WS_ALLOC(float*, gsum,  (size_t)N_GRAPHS*ALLF*4)
    WS_ALLOC(float*, gcnt,  (size_t)N_GRAPHS*4)
    WS_ALLOC(unsigned short*, feats_bf,  (size_t)N_NODES*KD*2)
    WS_ALLOC(unsigned short*, constpack, (size_t)5000*4*3*64*8*2)   // 61.44 MB
    WS_ALLOC(unsigned short*, W1p,  (size_t)NK*21*5*64*8*2)
    WS_ALLOC(unsigned short*, W2p,  (size_t)NK*2*11*64*8*2)
    WS_ALLOC(unsigned short*, W1An, (size_t)NK*4*2*64*8*2)
    WS_ALLOC(unsigned short*, W2An, (size_t)NK*2*2*64*8*2)
    (void)ws_size;

    hipMemsetAsync(deg,  0, (size_t)N_NODES*4, stream);
    hipMemsetAsync(gsum, 0, (size_t)N_GRAPHS*ALLF*4, stream);
    hipMemsetAsync(gcnt, 0, (size_t)N_GRAPHS*4, stream);

    pack_w1_kernel<<<(NK*21*5*64 + 255)/256, 256, 0, stream>>>(k_eW1, W1p);
    pack_w2_kernel<<<(NK*2*11*64 + 255)/256, 256, 0, stream>>>(k_eW2, W2p);
    pack_nw_kernel<<<(NK*4*2*64 + NK*2*2*64 + 255)/256, 256, 0, stream>>>(k_nW1, k_nW2, W1An, W2An);
    embed_nodes_kernel<<<N_NODES/8, 256, 0, stream>>>(props, embed_W, embed_b, batch,
                                                      feats, feats_bf, gsum, gcnt);
    edge_prep_kernel<<<N_EDGES/64, 256, 0, stream>>>(edge_props, positions, ei, eeW, eeb,
                                                     rel, deg, constpack);

    for (int k = 0; k < NK; ++k) {
        hipMemsetAsync(msum, 0, (size_t)N_NODES*KD*4, stream);
        edge_mlp_mfma<<<N_EDGES/64, 256, 0, stream>>>(
            feats_bf, constpack, rel, ei,
            W1p + (size_t)k*21*5*512, W2p + (size_t)k*2*11*512,
            k_eW1 + (size_t)k*EIN*EIN2 + 128*EIN2,
            k_eb1 + (size_t)k*EIN2, k_eb2 + (size_t)k*MD,
            k_eln_g + (size_t)k*MD, k_eln_b + (size_t)k*MD, msum);
        node_mlp_mfma<<<(N_NODES + 63)/64, 256, 0, stream>>>(
            msum, deg,
            W1An + (size_t)k*4*2*512, W2An + (size_t)k*2*2*512,
            k_nb1 + (size_t)k*64, k_nb2 + (size_t)k*32,
            k_eln_g + (size_t)k*MD, k_eln_b + (size_t)k*MD,
            k_n1g + (size_t)k*KD, k_n1b + (size_t)k*KD,
            k_n2g + (size_t)k*KD, k_n2b + (size_t)k*KD,
            batch, feats, feats_bf, gsum, k+1);
    }

    fnn_kernel<<<N_GRAPHS, 256, 0, stream>>>(gsum, gcnt, fnn_W0, fnn_b0, fnn_W1, fnn_b1,
                                             fnn_W2, fnn_b2, fnn_W3, fnn_b3, out);
}

// Round 5
// 882.277 us; speedup vs baseline: 2.0711x; 2.0711x over previous
//
#include <hip/hip_runtime.h>
#include <math.h>

#define N_NODES 20000
#define N_EDGES 320000
#define N_GRAPHS 64
#define PD 9
#define KD 32
#define MD 32
#define NK 5
#define EIN 161
#define EIN2 322
#define ALLF (KD*(NK+1))   // 192
#define LN_EPS 1e-5f

typedef __attribute__((ext_vector_type(8))) short short8;
typedef __attribute__((ext_vector_type(4))) float f32x4;
typedef __attribute__((ext_vector_type(4))) unsigned u32x4;
typedef __attribute__((ext_vector_type(2))) unsigned u32x2;
typedef __attribute__((ext_vector_type(4))) int i32x4;

__device__ __forceinline__ float silu_f(float x) { return x / (1.f + __expf(-x)); }

__device__ __forceinline__ unsigned short f2bf(float x) {
    union { float f; unsigned u; } v; v.f = x;
    unsigned r = v.u + 0x7FFFu + ((v.u >> 16) & 1u);
    return (unsigned short)(r >> 16);
}

__device__ __forceinline__ unsigned cvt_pk_bf16(float lo, float hi) {
    unsigned r;
    asm("v_cvt_pk_bf16_f32 %0, %1, %2" : "=v"(r) : "v"(lo), "v"(hi));
    return r;
}

// ---------------- weight packing: W1 -> bf16 MFMA A/B-frag order ----------------
// packed K (160): 0-31 feats_dst, 32-63 feats_src, 64-95 sin, 96-127 cos,
// 128-159 edge_feats (orig rows 129..160). Orig row 128 (rel_dist) is a rank-1
// epilogue update. Layout: [k][nt(21)][kb(5)][lane(64)][i(8)]
__global__ __launch_bounds__(256) void pack_w1_kernel(
    const float* __restrict__ eW1, unsigned short* __restrict__ W1p)
{
    int fid = blockIdx.x * 256 + threadIdx.x;
    if (fid >= NK*21*5*64) return;
    int kk = fid / (21*5*64);
    int r  = fid % (21*5*64);
    int nt = r / (5*64);
    int r2 = r % (5*64);
    int kb = r2 >> 6;
    int l  = r2 & 63;
    int q = l >> 4, el = l & 15;
    int n = 16*nt + el;
    short8 out;
    #pragma unroll
    for (int i = 0; i < 8; ++i) {
        int kp = 32*kb + 8*q + i;
        int orig = (kp < 128) ? kp : kp + 1; // skip rel_dist row 128
        float v = (n < EIN2) ? eW1[((size_t)kk*EIN + orig)*EIN2 + n] : 0.f;
        out[i] = (short)f2bf(v);
    }
    *(short8*)&W1p[(size_t)fid*8] = out;
}

// W2 packed: K2 = 352 (11 kb blocks; rows >=322 zero). [k][nt2(2)][kb2(11)][lane][i]
__global__ __launch_bounds__(256) void pack_w2_kernel(
    const float* __restrict__ eW2, unsigned short* __restrict__ W2p)
{
    int fid = blockIdx.x * 256 + threadIdx.x;
    if (fid >= NK*2*11*64) return;
    int kk = fid / (2*11*64);
    int r  = fid % (2*11*64);
    int nt2 = r / (11*64);
    int r2  = r % (11*64);
    int kb2 = r2 >> 6;
    int l   = r2 & 63;
    int q = l >> 4, el = l & 15;
    int n = 16*nt2 + el;
    short8 out;
    #pragma unroll
    for (int i = 0; i < 8; ++i) {
        int k2 = 32*kb2 + 8*q + i;
        float v = (k2 < EIN2) ? eW2[((size_t)kk*EIN2 + k2)*MD + n] : 0.f;
        out[i] = (short)f2bf(v);
    }
    *(short8*)&W2p[(size_t)fid*8] = out;
}

// node weights: W1A [kk][mt(4)][kb(2)][lane][8]; W2A [kk][mt2(2)][kb(2)][lane][8]
__global__ __launch_bounds__(256) void pack_nw_kernel(
    const float* __restrict__ nW1, const float* __restrict__ nW2,
    unsigned short* __restrict__ W1A, unsigned short* __restrict__ W2A)
{
    int fid = blockIdx.x * 256 + threadIdx.x;
    const int tot1 = NK*4*2*64;
    const int tot2 = NK*2*2*64;
    if (fid < tot1) {
        int kk = fid / (4*2*64);
        int r  = fid % (4*2*64);
        int mt = r / 128;
        int r2 = r % 128;
        int kb = r2 >> 6;
        int l  = r2 & 63;
        int q = l >> 4, el = l & 15;
        short8 out;
        #pragma unroll
        for (int i = 0; i < 8; ++i)
            out[i] = (short)f2bf(nW1[((size_t)kk*64 + 32*kb + 8*q + i)*64 + 16*mt + el]);
        *(short8*)&W1A[(size_t)fid*8] = out;
    } else if (fid < tot1 + tot2) {
        int f2 = fid - tot1;
        int kk = f2 / (2*2*64);
        int r  = f2 % (2*2*64);
        int mt2 = r / 128;
        int r2  = r % 128;
        int kb  = r2 >> 6;
        int l   = r2 & 63;
        int q = l >> 4, el = l & 15;
        short8 out;
        #pragma unroll
        for (int i = 0; i < 8; ++i)
            out[i] = (short)f2bf(nW2[((size_t)kk*64 + 32*kb + 8*q + i)*32 + 16*mt2 + el]);
        *(short8*)&W2A[(size_t)f2*8] = out;
    }
}

// ---------------- node embed ----------------
__global__ __launch_bounds__(256) void embed_nodes_kernel(
    const float* __restrict__ props, const float* __restrict__ W,
    const float* __restrict__ b,
    float* __restrict__ feats, unsigned short* __restrict__ feats_bf,
    float* __restrict__ allf)
{
    int t = threadIdx.x;
    int n = blockIdx.x * 8 + (t >> 5);
    int f = t & 31;
    if (n >= N_NODES) return;
    float acc = b[f];
    #pragma unroll
    for (int i = 0; i < PD; ++i) acc += props[n*PD + i] * W[i*KD + f];
    feats[n*KD + f] = acc;
    feats_bf[n*KD + f] = f2bf(acc);
    allf[(size_t)n*ALLF + f] = acc;
}

// ------- edge prep (fused): edge embed + rel_dist + deg + constpack -------
// constpack per 64-edge block b: [w(4)][kbr(3: sin,cos,ef)][lane(64)][i(8)] bf16
__global__ __launch_bounds__(256) void edge_prep_kernel(
    const float* __restrict__ edge_props, const float* __restrict__ positions,
    const int* __restrict__ ei, const float* __restrict__ W,
    const float* __restrict__ b, float* __restrict__ rel,
    float* __restrict__ deg, unsigned short* __restrict__ constpack)
{
    __shared__ float ef[64*32];
    __shared__ float rdl[64];
    int t = threadIdx.x;
    int b0 = blockIdx.x;
    int e0 = b0 * 64;

    {
        int e = t >> 2, sub = t & 3;
        float acc[8];
        #pragma unroll
        for (int j = 0; j < 8; ++j) acc[j] = b[sub*8 + j];
        #pragma unroll
        for (int i = 0; i < PD; ++i) {
            float p = edge_props[(size_t)(e0 + e)*PD + i];
            #pragma unroll
            for (int j = 0; j < 8; ++j) acc[j] += p * W[i*KD + sub*8 + j];
        }
        #pragma unroll
        for (int j = 0; j < 8; ++j) ef[e*32 + sub*8 + j] = acc[j];
    }
    if (t < 64) {
        int e = e0 + t;
        int s = ei[e], d = ei[N_EDGES + e];
        float dx = positions[s*3+0] - positions[d*3+0];
        float dy = positions[s*3+1] - positions[d*3+1];
        float dz = positions[s*3+2] - positions[d*3+2];
        float rd = dx*dx + dy*dy + dz*dz;
        rdl[t] = rd;
        rel[e] = rd;
        atomicAdd(&deg[d], 1.f);
    }
    __syncthreads();

    int l = t & 63, w = t >> 6;
    int q = l >> 4, el = l & 15;
    float rd = rdl[16*w + el];
    #pragma unroll
    for (int kbr = 0; kbr < 3; ++kbr) {
        short8 out;
        #pragma unroll
        for (int i = 0; i < 8; ++i) {
            int k = 8*q + i;
            float v;
            if (kbr == 0)      v = sinf(ldexpf(rd, -k));
            else if (kbr == 1) v = cosf(ldexpf(rd, -k));
            else               v = ef[(16*w + el)*32 + k];
            out[i] = (short)f2bf(v);
        }
        *(short8*)&constpack[((((size_t)b0*4 + w)*3 + kbr)*64 + l)*8] = out;
    }
}

// ---------------- MFMA edge MLP (swapped GEMM1, register exchange) ----------------
// 64 edges/block, 4 waves x 16 edges. No LDS, no barriers.
// GEMM1: acc = mfma(W1frag, hfrag) -> lane holds n1=16nt+4q+j for ITS edge el.
// silu -> cvt_pk -> 4x shfl redistributes to GEMM2 A-frag in registers.
__global__ __launch_bounds__(256) void edge_mlp_mfma(
    const unsigned short* __restrict__ feats_bf,
    const unsigned short* __restrict__ constpack,
    const float* __restrict__ rel, const int* __restrict__ ei,
    const unsigned short* __restrict__ W1p, const unsigned short* __restrict__ W2p,
    const float* __restrict__ w1rd, const float* __restrict__ eb1,
    const float* __restrict__ eb2, const float* __restrict__ lg,
    const float* __restrict__ lb, float* __restrict__ msum)
{
    int t = threadIdx.x;
    int b = blockIdx.x;
    int w = t >> 6, l = t & 63, q = l >> 4, el = l & 15;
    int e0 = b * 64;
    int eMine = e0 + 16*w + el;
    int srcn = ei[eMine];
    int dstn = ei[N_EDGES + eMine];
    float rd = rel[eMine];

    short8 a0 = *(const short8*)&feats_bf[(size_t)dstn*KD + 8*q];
    short8 a1 = *(const short8*)&feats_bf[(size_t)srcn*KD + 8*q];
    const unsigned short* cp = &constpack[((size_t)(b*4 + w)*3)*512 + (size_t)l*8];
    short8 a2 = *(const short8*)&cp[0];
    short8 a3 = *(const short8*)&cp[512];
    short8 a4 = *(const short8*)&cp[1024];

    unsigned h1r[44];
    #pragma unroll
    for (int i = 0; i < 44; ++i) h1r[i] = 0u;

    const int sA = 32*(q & 1) + el;   // exchange source lanes
    const int sB = sA + 16;
    const int myp = q >> 1;           // parity this lane consumes

    #pragma unroll
    for (int nt = 0; nt < 21; ++nt) {
        f32x4 acc = {0.f, 0.f, 0.f, 0.f};
        const unsigned short* wb = &W1p[(size_t)(nt*5)*512 + (size_t)l*8];
        acc = __builtin_amdgcn_mfma_f32_16x16x32_bf16(*(const short8*)&wb[0],    a0, acc, 0, 0, 0);
        acc = __builtin_amdgcn_mfma_f32_16x16x32_bf16(*(const short8*)&wb[512],  a1, acc, 0, 0, 0);
        acc = __builtin_amdgcn_mfma_f32_16x16x32_bf16(*(const short8*)&wb[1024], a2, acc, 0, 0, 0);
        acc = __builtin_amdgcn_mfma_f32_16x16x32_bf16(*(const short8*)&wb[1536], a3, acc, 0, 0, 0);
        acc = __builtin_amdgcn_mfma_f32_16x16x32_bf16(*(const short8*)&wb[2048], a4, acc, 0, 0, 0);

        float vj[4];
        if (nt < 20) {
            f32x4 be = *(const f32x4*)&eb1[16*nt + 4*q];
            f32x4 wr = *(const f32x4*)&w1rd[16*nt + 4*q];
            #pragma unroll
            for (int j = 0; j < 4; ++j)
                vj[j] = silu_f(acc[j] + be[j] + rd * wr[j]);
        } else {
            int nb = 320 + 4*q;
            #pragma unroll
            for (int j = 0; j < 4; ++j) {
                int n1 = nb + j;
                bool ok = n1 < EIN2;
                float be = ok ? eb1[n1] : 0.f;
                float wr = ok ? w1rd[n1] : 0.f;
                float v = silu_f(acc[j] + be + rd * wr);
                vj[j] = ok ? v : 0.f;
            }
        }

        unsigned P0 = cvt_pk_bf16(vj[0], vj[1]);
        unsigned P1 = cvt_pk_bf16(vj[2], vj[3]);
        unsigned g0 = (unsigned)__shfl((int)P0, sA);
        unsigned g1 = (unsigned)__shfl((int)P1, sA);
        unsigned g2 = (unsigned)__shfl((int)P0, sB);
        unsigned g3 = (unsigned)__shfl((int)P1, sB);
        const int kb2 = nt >> 1;
        bool recv = (myp == (nt & 1));
        h1r[kb2*4+0] = recv ? g0 : h1r[kb2*4+0];
        h1r[kb2*4+1] = recv ? g1 : h1r[kb2*4+1];
        h1r[kb2*4+2] = recv ? g2 : h1r[kb2*4+2];
        h1r[kb2*4+3] = recv ? g3 : h1r[kb2*4+3];
    }

    // GEMM2: A = h1 (register frags), B = W2p. K=352, N=32.
    f32x4 acc20 = {0.f, 0.f, 0.f, 0.f};
    f32x4 acc21 = {0.f, 0.f, 0.f, 0.f};
    #pragma unroll
    for (int kb2 = 0; kb2 < 11; ++kb2) {
        u32x4 hv = { h1r[kb2*4+0], h1r[kb2*4+1], h1r[kb2*4+2], h1r[kb2*4+3] };
        short8 av = __builtin_bit_cast(short8, hv);
        short8 b0 = *(const short8*)&W2p[(size_t)kb2*512 + (size_t)l*8];
        short8 b1 = *(const short8*)&W2p[(size_t)(11 + kb2)*512 + (size_t)l*8];
        acc20 = __builtin_amdgcn_mfma_f32_16x16x32_bf16(av, b0, acc20, 0, 0, 0);
        acc21 = __builtin_amdgcn_mfma_f32_16x16x32_bf16(av, b1, acc21, 0, 0, 0);
    }

    // epilogue: silu -> per-edge LayerNorm (32 cols) -> atomic aggregate.
    // lane (q,el): edge 16w+4q+j (row), cols el and 16+el.
    i32x4 dstv = *(const i32x4*)&ei[N_EDGES + e0 + 16*w + 4*q];
    float e20 = eb2[el], e21 = eb2[16 + el];
    float g0v = lg[el],  g1v = lg[16 + el];
    float b0v = lb[el],  b1v = lb[16 + el];
    #pragma unroll
    for (int j = 0; j < 4; ++j) {
        float m0 = silu_f(acc20[j] + e20);
        float m1 = silu_f(acc21[j] + e21);
        float s = m0 + m1;
        s += __shfl_xor(s, 1, 16); s += __shfl_xor(s, 2, 16);
        s += __shfl_xor(s, 4, 16); s += __shfl_xor(s, 8, 16);
        float mu = s * (1.f/32.f);
        float d0 = m0 - mu, d1 = m1 - mu;
        float vv = d0*d0 + d1*d1;
        vv += __shfl_xor(vv, 1, 16); vv += __shfl_xor(vv, 2, 16);
        vv += __shfl_xor(vv, 4, 16); vv += __shfl_xor(vv, 8, 16);
        float rs = rsqrtf(vv * (1.f/32.f) + LN_EPS);
        int dst = dstv[j];
        atomicAdd(&msum[(size_t)dst*MD + el],      d0*rs*g0v + b0v);
        atomicAdd(&msum[(size_t)dst*MD + 16 + el], d1*rs*g1v + b1v);
    }
}

// ---------------- MFMA node MLP: 64 nodes/block, 16/wave ----------------
__global__ __launch_bounds__(256) void node_mlp_mfma(
    const float* __restrict__ msum, const float* __restrict__ deg,
    const unsigned short* __restrict__ W1A, const unsigned short* __restrict__ W2A,
    const float* __restrict__ nb1, const float* __restrict__ nb2,
    const float* __restrict__ eln_g, const float* __restrict__ eln_b,
    const float* __restrict__ n1g, const float* __restrict__ n1b,
    const float* __restrict__ n2g, const float* __restrict__ n2b,
    float* __restrict__ feats, unsigned short* __restrict__ feats_bf,
    float* __restrict__ allf, int kslot)
{
    int t = threadIdx.x;
    int w = t >> 6, l = t & 63, q = l >> 4, el = l & 15;
    int nd = blockIdx.x*64 + 16*w + el;
    bool okn = nd < N_NODES;
    size_t ndc = okn ? (size_t)nd : (size_t)(N_NODES - 1);

    // ---- load input, dual group-LN, pack to B-frags ----
    float x[2][8];
    {
        f32x4 f0 = *(const f32x4*)&feats[ndc*KD + 8*q];
        f32x4 f1 = *(const f32x4*)&feats[ndc*KD + 8*q + 4];
        float inv = 1.f / fmaxf(deg[ndc], 1.f);
        f32x4 m0 = *(const f32x4*)&msum[ndc*KD + 8*q];
        f32x4 m1 = *(const f32x4*)&msum[ndc*KD + 8*q + 4];
        #pragma unroll
        for (int j = 0; j < 4; ++j) {
            x[0][j] = f0[j]; x[0][4+j] = f1[j];
            x[1][j] = m0[j]*inv; x[1][4+j] = m1[j]*inv;
        }
    }
    short8 xf[2];
    #pragma unroll
    for (int kb = 0; kb < 2; ++kb) {
        float s = 0.f;
        #pragma unroll
        for (int i = 0; i < 8; ++i) s += x[kb][i];
        s += __shfl_xor(s, 16); s += __shfl_xor(s, 32);
        float mu = s * (1.f/32.f);
        float vv = 0.f;
        #pragma unroll
        for (int i = 0; i < 8; ++i) { float d = x[kb][i] - mu; vv += d*d; }
        vv += __shfl_xor(vv, 16); vv += __shfl_xor(vv, 32);
        float rs = rsqrtf(vv * (1.f/32.f) + LN_EPS);
        const float* gp = kb ? eln_g : n1g;
        const float* bp = kb ? eln_b : n1b;
        f32x4 ga = *(const f32x4*)&gp[8*q];
        f32x4 gb = *(const f32x4*)&gp[8*q + 4];
        f32x4 ba = *(const f32x4*)&bp[8*q];
        f32x4 bb = *(const f32x4*)&bp[8*q + 4];
        float z[8];
        #pragma unroll
        for (int j = 0; j < 4; ++j) {
            z[j]   = (x[kb][j]   - mu)*rs*ga[j] + ba[j];
            z[4+j] = (x[kb][4+j] - mu)*rs*gb[j] + bb[j];
        }
        u32x4 pv = { cvt_pk_bf16(z[0], z[1]), cvt_pk_bf16(z[2], z[3]),
                     cvt_pk_bf16(z[4], z[5]), cvt_pk_bf16(z[6], z[7]) };
        xf[kb] = __builtin_bit_cast(short8, pv);
    }

    // ---- stage 1: h = silu(x @ W1 + b1), swapped MFMA + exchange ----
    const int sA = 32*(q & 1) + el;
    const int sB = sA + 16;
    const int myp = q >> 1;
    unsigned hr[8];
    #pragma unroll
    for (int i = 0; i < 8; ++i) hr[i] = 0u;

    #pragma unroll
    for (int mt = 0; mt < 4; ++mt) {
        f32x4 acc = {0.f, 0.f, 0.f, 0.f};
        acc = __builtin_amdgcn_mfma_f32_16x16x32_bf16(
            *(const short8*)&W1A[(size_t)(mt*2 + 0)*512 + (size_t)l*8], xf[0], acc, 0, 0, 0);
        acc = __builtin_amdgcn_mfma_f32_16x16x32_bf16(
            *(const short8*)&W1A[(size_t)(mt*2 + 1)*512 + (size_t)l*8], xf[1], acc, 0, 0, 0);
        f32x4 b1v = *(const f32x4*)&nb1[16*mt + 4*q];
        float vj[4];
        #pragma unroll
        for (int j = 0; j < 4; ++j) vj[j] = silu_f(acc[j] + b1v[j]);
        unsigned P0 = cvt_pk_bf16(vj[0], vj[1]);
        unsigned P1 = cvt_pk_bf16(vj[2], vj[3]);
        unsigned g0 = (unsigned)__shfl((int)P0, sA);
        unsigned g1 = (unsigned)__shfl((int)P1, sA);
        unsigned g2 = (unsigned)__shfl((int)P0, sB);
        unsigned g3 = (unsigned)__shfl((int)P1, sB);
        const int kb2 = mt >> 1;
        bool recv = (myp == (mt & 1));
        hr[kb2*4+0] = recv ? g0 : hr[kb2*4+0];
        hr[kb2*4+1] = recv ? g1 : hr[kb2*4+1];
        hr[kb2*4+2] = recv ? g2 : hr[kb2*4+2];
        hr[kb2*4+3] = recv ? g3 : hr[kb2*4+3];
    }

    // ---- stage 2: out = h @ W2 + b2 (swapped), then LN2 + residual ----
    u32x4 h0v = { hr[0], hr[1], hr[2], hr[3] };
    u32x4 h1v = { hr[4], hr[5], hr[6], hr[7] };
    short8 hf0 = __builtin_bit_cast(short8, h0v);
    short8 hf1 = __builtin_bit_cast(short8, h1v);
    float o[2][4];
    #pragma unroll
    for (int mt2 = 0; mt2 < 2; ++mt2) {
        f32x4 acc = {0.f, 0.f, 0.f, 0.f};
        acc = __builtin_amdgcn_mfma_f32_16x16x32_bf16(
            *(const short8*)&W2A[(size_t)(mt2*2 + 0)*512 + (size_t)l*8], hf0, acc, 0, 0, 0);
        acc = __builtin_amdgcn_mfma_f32_16x16x32_bf16(
            *(const short8*)&W2A[(size_t)(mt2*2 + 1)*512 + (size_t)l*8], hf1, acc, 0, 0, 0);
        f32x4 b2v = *(const f32x4*)&nb2[16*mt2 + 4*q];
        #pragma unroll
        for (int j = 0; j < 4; ++j) o[mt2][j] = acc[j] + b2v[j];
    }
    float s2 = 0.f;
    #pragma unroll
    for (int mt2 = 0; mt2 < 2; ++mt2)
        #pragma unroll
        for (int j = 0; j < 4; ++j) s2 += o[mt2][j];
    s2 += __shfl_xor(s2, 16); s2 += __shfl_xor(s2, 32);
    float mu2 = s2 * (1.f/32.f);
    float vv2 = 0.f;
    #pragma unroll
    for (int mt2 = 0; mt2 < 2; ++mt2)
        #pragma unroll
        for (int j = 0; j < 4; ++j) { float d = o[mt2][j] - mu2; vv2 += d*d; }
    vv2 += __shfl_xor(vv2, 16); vv2 += __shfl_xor(vv2, 32);
    float rs2 = rsqrtf(vv2 * (1.f/32.f) + LN_EPS);

    #pragma unroll
    for (int mt2 = 0; mt2 < 2; ++mt2) {
        f32x4 gv = *(const f32x4*)&n2g[16*mt2 + 4*q];
        f32x4 bv = *(const f32x4*)&n2b[16*mt2 + 4*q];
        f32x4 fold = *(const f32x4*)&feats[ndc*KD + 16*mt2 + 4*q];
        f32x4 nf;
        #pragma unroll
        for (int j = 0; j < 4; ++j)
            nf[j] = fold[j] + (o[mt2][j] - mu2)*rs2*gv[j] + bv[j];
        if (okn) {
            *(f32x4*)&feats[(size_t)nd*KD + 16*mt2 + 4*q] = nf;
            u32x2 pb = { cvt_pk_bf16(nf[0], nf[1]), cvt_pk_bf16(nf[2], nf[3]) };
            *(u32x2*)&feats_bf[(size_t)nd*KD + 16*mt2 + 4*q] = pb;
            *(f32x4*)&allf[(size_t)nd*ALLF + kslot*KD + 16*mt2 + 4*q] = nf;
        }
    }
}

// ---------------- mean pool: 4 blocks per graph, lane<->column ----------------
__global__ __launch_bounds__(256) void pool_kernel(
    const float* __restrict__ allf, const int* __restrict__ batch,
    float* __restrict__ gsum, float* __restrict__ gcnt)
{
    int b = blockIdx.x, t = threadIdx.x;
    int g = b >> 2, part = b & 3;
    int lo = 0, hi = N_NODES;
    while (lo < hi) { int m = (lo+hi) >> 1; if (batch[m] < g) lo = m+1; else hi = m; }
    int start = lo;
    hi = N_NODES;
    while (lo < hi) { int m = (lo+hi) >> 1; if (batch[m] < g+1) lo = m+1; else hi = m; }
    int end = lo;
    if (part == 0 && t == 0) gcnt[g] = (float)(end - start);
    int len = end - start;
    int chunk = (len + 3) >> 2;
    int s = start + part*chunk;
    int e = min(end, s + chunk);
    if (t < ALLF && e > s) {
        float acc = 0.f;
        for (int n = s; n < e; ++n) acc += allf[(size_t)n*ALLF + t];
        atomicAdd(&gsum[g*ALLF + t], acc);
    }
}

// ---------------- final FNN: block per graph ----------------
__global__ __launch_bounds__(256) void fnn_kernel(
    const float* __restrict__ gsum, const float* __restrict__ gcnt,
    const float* __restrict__ W0, const float* __restrict__ b0,
    const float* __restrict__ W1, const float* __restrict__ b1,
    const float* __restrict__ W2, const float* __restrict__ b2,
    const float* __restrict__ W3, const float* __restrict__ b3,
    float* __restrict__ out)
{
    __shared__ float xs[256];
    __shared__ float partial[4];
    int g = blockIdx.x, t = threadIdx.x;
    float inv = 1.f / fmaxf(gcnt[g], 1.f);
    if (t < ALLF) xs[t] = gsum[g*ALLF + t] * inv;
    __syncthreads();
    float acc = b0[t];
    for (int i = 0; i < ALLF; ++i) acc += xs[i] * W0[i*256 + t];
    acc = silu_f(acc);
    __syncthreads(); xs[t] = acc; __syncthreads();
    acc = b1[t];
    for (int i = 0; i < 256; ++i) acc += xs[i] * W1[i*256 + t];
    acc = silu_f(acc);
    __syncthreads(); xs[t] = acc; __syncthreads();
    acc = b2[t];
    for (int i = 0; i < 256; ++i) acc += xs[i] * W2[i*256 + t];
    acc = silu_f(acc);
    __syncthreads(); xs[t] = acc; __syncthreads();
    float v = xs[t] * W3[t];
    #pragma unroll
    for (int m = 32; m; m >>= 1) v += __shfl_xor(v, m, 64);
    if ((t & 63) == 0) partial[t >> 6] = v;
    __syncthreads();
    if (t == 0) out[g] = partial[0] + partial[1] + partial[2] + partial[3] + b3[0];
}

extern "C" void kernel_launch(void* const* d_in, const int* in_sizes, int n_in,
                              void* d_out, int out_size, void* d_ws, size_t ws_size,
                              hipStream_t stream) {
    const float* props      = (const float*)d_in[0];
    const float* positions  = (const float*)d_in[1];
    const float* edge_props = (const float*)d_in[2];
    const float* embed_W    = (const float*)d_in[3];
    const float* embed_b    = (const float*)d_in[4];
    const float* eeW        = (const float*)d_in[5];
    const float* eeb        = (const float*)d_in[6];
    const float* k_eW1      = (const float*)d_in[7];
    const float* k_eb1      = (const float*)d_in[8];
    const float* k_eW2      = (const float*)d_in[9];
    const float* k_eb2      = (const float*)d_in[10];
    const float* k_eln_g    = (const float*)d_in[11];
    const float* k_eln_b    = (const float*)d_in[12];
    const float* k_n1g      = (const float*)d_in[13];
    const float* k_n1b      = (const float*)d_in[14];
    const float* k_n2g      = (const float*)d_in[15];
    const float* k_n2b      = (const float*)d_in[16];
    const float* k_nW1      = (const float*)d_in[17];
    const float* k_nb1      = (const float*)d_in[18];
    const float* k_nW2      = (const float*)d_in[19];
    const float* k_nb2      = (const float*)d_in[20];
    const float* fnn_W0     = (const float*)d_in[21];
    const float* fnn_b0     = (const float*)d_in[22];
    const float* fnn_W1     = (const float*)d_in[23];
    const float* fnn_b1     = (const float*)d_in[24];
    const float* fnn_W2     = (const float*)d_in[25];
    const float* fnn_b2     = (const float*)d_in[26];
    const float* fnn_W3     = (const float*)d_in[27];
    const float* fnn_b3     = (const float*)d_in[28];
    const int*   ei         = (const int*)d_in[29];
    const int*   batch      = (const int*)d_in[30];
    float* out = (float*)d_out;

    // ---- workspace layout (bytes, 256-aligned) ----
    char* wsb = (char*)d_ws;
    size_t off = 0;
    #define WS_ALLOC(ptr_t, name, bytes) ptr_t name = (ptr_t)(wsb + off); off += (((size_t)(bytes)) + 255) & ~(size_t)255;
    WS_ALLOC(float*, feats, (size_t)N_NODES*KD*4)
    WS_ALLOC(float*, msum,  (size_t)N_NODES*KD*4)
    WS_ALLOC(float*, deg,   (size_t)N_NODES*4)
    WS_ALLOC(float*, rel,   (size_t)N_EDGES*4)
    WS_ALLOC(float*, gsum,  (size_t)N_GRAPHS*ALLF*4)
    WS_ALLOC(float*, gcnt,  (size_t)N_GRAPHS*4)
    WS_ALLOC(float*, allf,  (size_t)N_NODES*ALLF*4)
    WS_ALLOC(unsigned short*, feats_bf,  (size_t)N_NODES*KD*2)
    WS_ALLOC(unsigned short*, constpack, (size_t)5000*4*3*64*8*2)   // 61.44 MB
    WS_ALLOC(unsigned short*, W1p,  (size_t)NK*21*5*64*8*2)
    WS_ALLOC(unsigned short*, W2p,  (size_t)NK*2*11*64*8*2)
    WS_ALLOC(unsigned short*, W1An, (size_t)NK*4*2*64*8*2)
    WS_ALLOC(unsigned short*, W2An, (size_t)NK*2*2*64*8*2)
    (void)ws_size;

    hipMemsetAsync(deg,  0, (size_t)N_NODES*4, stream);
    hipMemsetAsync(gsum, 0, (size_t)N_GRAPHS*ALLF*4, stream);

    pack_w1_kernel<<<(NK*21*5*64 + 255)/256, 256, 0, stream>>>(k_eW1, W1p);
    pack_w2_kernel<<<(NK*2*11*64 + 255)/256, 256, 0, stream>>>(k_eW2, W2p);
    pack_nw_kernel<<<(NK*4*2*64 + NK*2*2*64 + 255)/256, 256, 0, stream>>>(k_nW1, k_nW2, W1An, W2An);
    embed_nodes_kernel<<<N_NODES/8, 256, 0, stream>>>(props, embed_W, embed_b,
                                                      feats, feats_bf, allf);
    edge_prep_kernel<<<N_EDGES/64, 256, 0, stream>>>(edge_props, positions, ei, eeW, eeb,
                                                     rel, deg, constpack);

    for (int k = 0; k < NK; ++k) {
        hipMemsetAsync(msum, 0, (size_t)N_NODES*KD*4, stream);
        edge_mlp_mfma<<<N_EDGES/64, 256, 0, stream>>>(
            feats_bf, constpack, rel, ei,
            W1p + (size_t)k*21*5*512, W2p + (size_t)k*2*11*512,
            k_eW1 + (size_t)k*EIN*EIN2 + 128*EIN2,
            k_eb1 + (size_t)k*EIN2, k_eb2 + (size_t)k*MD,
            k_eln_g + (size_t)k*MD, k_eln_b + (size_t)k*MD, msum);
        node_mlp_mfma<<<(N_NODES + 63)/64, 256, 0, stream>>>(
            msum, deg,
            W1An + (size_t)k*4*2*512, W2An + (size_t)k*2*2*512,
            k_nb1 + (size_t)k*64, k_nb2 + (size_t)k*32,
            k_eln_g + (size_t)k*MD, k_eln_b + (size_t)k*MD,
            k_n1g + (size_t)k*KD, k_n1b + (size_t)k*KD,
            k_n2g + (size_t)k*KD, k_n2b + (size_t)k*KD,
            feats, feats_bf, allf, k+1);
    }

    pool_kernel<<<N_GRAPHS*4, 256, 0, stream>>>(allf, batch, gsum, gcnt);
    fnn_kernel<<<N_GRAPHS, 256, 0, stream>>>(gsum, gcnt, fnn_W0, fnn_b0, fnn_W1, fnn_b1,
                                             fnn_W2, fnn_b2, fnn_W3, fnn_b3, out);
}

// Round 6
// 829.758 us; speedup vs baseline: 2.2021x; 1.0633x over previous
//
#include <hip/hip_runtime.h>
#include <math.h>

#define N_NODES 20000
#define N_EDGES 320000
#define N_GRAPHS 64
#define PD 9
#define KD 32
#define MD 32
#define NK 5
#define EIN 161
#define EIN2 322
#define ALLF (KD*(NK+1))   // 192
#define LN_EPS 1e-5f

typedef __attribute__((ext_vector_type(8))) short short8;
typedef __attribute__((ext_vector_type(4))) float f32x4;
typedef __attribute__((ext_vector_type(4))) unsigned u32x4;
typedef __attribute__((ext_vector_type(2))) unsigned u32x2;
typedef __attribute__((ext_vector_type(4))) int i32x4;

__device__ __forceinline__ float silu_f(float x) { return x / (1.f + __expf(-x)); }

__device__ __forceinline__ unsigned short f2bf(float x) {
    union { float f; unsigned u; } v; v.f = x;
    unsigned r = v.u + 0x7FFFu + ((v.u >> 16) & 1u);
    return (unsigned short)(r >> 16);
}

__device__ __forceinline__ unsigned cvt_pk_bf16(float lo, float hi) {
    unsigned r;
    asm("v_cvt_pk_bf16_f32 %0, %1, %2" : "=v"(r) : "v"(lo), "v"(hi));
    return r;
}

// ---------------- weight packing: W1 -> bf16 MFMA A-frag order, PERMUTED ----------------
// packed K (160): 0-31 feats_dst, 32-63 feats_src, 64-95 sin, 96-127 cos,
// 128-159 edge_feats (orig rows 129..160). Orig row 128 (rel_dist) is a rank-1
// epilogue update. Layout: [k][nt(21)][kb(5)][lane(64)][i(8)].
// COLUMN PERMUTATION: tile nt=(m=nt>>1, t=nt&1), tile position p -> original
// column n = 32m + 8*(p>>2) + 4*t + (p&3). This makes GEMM1's C/D land each
// lane's 8 consecutive k2 values for GEMM2's A-frag with NO cross-lane exchange.
__global__ __launch_bounds__(256) void pack_w1_kernel(
    const float* __restrict__ eW1, unsigned short* __restrict__ W1p)
{
    int fid = blockIdx.x * 256 + threadIdx.x;
    if (fid >= NK*21*5*64) return;
    int kk = fid / (21*5*64);
    int r  = fid % (21*5*64);
    int nt = r / (5*64);
    int r2 = r % (5*64);
    int kb = r2 >> 6;
    int l  = r2 & 63;
    int q = l >> 4, el = l & 15;
    int n = 32*(nt >> 1) + 8*(el >> 2) + 4*(nt & 1) + (el & 3);   // permuted column
    short8 out;
    #pragma unroll
    for (int i = 0; i < 8; ++i) {
        int kp = 32*kb + 8*q + i;
        int orig = (kp < 128) ? kp : kp + 1; // skip rel_dist row 128
        float v = (n < EIN2) ? eW1[((size_t)kk*EIN + orig)*EIN2 + n] : 0.f;
        out[i] = (short)f2bf(v);
    }
    *(short8*)&W1p[(size_t)fid*8] = out;
}

// W2 packed: K2 = 352 (11 kb blocks; rows >=322 zero). [k][nt2(2)][kb2(11)][lane][i]
__global__ __launch_bounds__(256) void pack_w2_kernel(
    const float* __restrict__ eW2, unsigned short* __restrict__ W2p)
{
    int fid = blockIdx.x * 256 + threadIdx.x;
    if (fid >= NK*2*11*64) return;
    int kk = fid / (2*11*64);
    int r  = fid % (2*11*64);
    int nt2 = r / (11*64);
    int r2  = r % (11*64);
    int kb2 = r2 >> 6;
    int l   = r2 & 63;
    int q = l >> 4, el = l & 15;
    int n = 16*nt2 + el;
    short8 out;
    #pragma unroll
    for (int i = 0; i < 8; ++i) {
        int k2 = 32*kb2 + 8*q + i;
        float v = (k2 < EIN2) ? eW2[((size_t)kk*EIN2 + k2)*MD + n] : 0.f;
        out[i] = (short)f2bf(v);
    }
    *(short8*)&W2p[(size_t)fid*8] = out;
}

// node weights: W1A [kk][mt(4)][kb(2)][lane][8] with the SAME m-dim permutation
// (orig row = 32*(mt>>1) + 8*(el>>2) + 4*(mt&1) + (el&3)); W2A unchanged.
__global__ __launch_bounds__(256) void pack_nw_kernel(
    const float* __restrict__ nW1, const float* __restrict__ nW2,
    unsigned short* __restrict__ W1A, unsigned short* __restrict__ W2A)
{
    int fid = blockIdx.x * 256 + threadIdx.x;
    const int tot1 = NK*4*2*64;
    const int tot2 = NK*2*2*64;
    if (fid < tot1) {
        int kk = fid / (4*2*64);
        int r  = fid % (4*2*64);
        int mt = r / 128;
        int r2 = r % 128;
        int kb = r2 >> 6;
        int l  = r2 & 63;
        int q = l >> 4, el = l & 15;
        int n = 32*(mt >> 1) + 8*(el >> 2) + 4*(mt & 1) + (el & 3);  // permuted
        short8 out;
        #pragma unroll
        for (int i = 0; i < 8; ++i)
            out[i] = (short)f2bf(nW1[((size_t)kk*64 + 32*kb + 8*q + i)*64 + n]);
        *(short8*)&W1A[(size_t)fid*8] = out;
    } else if (fid < tot1 + tot2) {
        int f2 = fid - tot1;
        int kk = f2 / (2*2*64);
        int r  = f2 % (2*2*64);
        int mt2 = r / 128;
        int r2  = r % 128;
        int kb  = r2 >> 6;
        int l   = r2 & 63;
        int q = l >> 4, el = l & 15;
        short8 out;
        #pragma unroll
        for (int i = 0; i < 8; ++i)
            out[i] = (short)f2bf(nW2[((size_t)kk*64 + 32*kb + 8*q + i)*32 + 16*mt2 + el]);
        *(short8*)&W2A[(size_t)f2*8] = out;
    }
}

// ---------------- node embed ----------------
__global__ __launch_bounds__(256) void embed_nodes_kernel(
    const float* __restrict__ props, const float* __restrict__ W,
    const float* __restrict__ b,
    float* __restrict__ feats, unsigned short* __restrict__ feats_bf,
    float* __restrict__ allf)
{
    int t = threadIdx.x;
    int n = blockIdx.x * 8 + (t >> 5);
    int f = t & 31;
    if (n >= N_NODES) return;
    float acc = b[f];
    #pragma unroll
    for (int i = 0; i < PD; ++i) acc += props[n*PD + i] * W[i*KD + f];
    feats[n*KD + f] = acc;
    feats_bf[n*KD + f] = f2bf(acc);
    allf[(size_t)n*ALLF + f] = acc;
}

// ------- edge prep (fused): edge embed + rel_dist + deg + constpack -------
// constpack per 64-edge block b: [w(4)][kbr(3: sin,cos,ef)][lane(64)][i(8)] bf16
__global__ __launch_bounds__(256) void edge_prep_kernel(
    const float* __restrict__ edge_props, const float* __restrict__ positions,
    const int* __restrict__ ei, const float* __restrict__ W,
    const float* __restrict__ b, float* __restrict__ rel,
    float* __restrict__ deg, unsigned short* __restrict__ constpack)
{
    __shared__ float ef[64*32];
    __shared__ float rdl[64];
    int t = threadIdx.x;
    int b0 = blockIdx.x;
    int e0 = b0 * 64;

    {
        int e = t >> 2, sub = t & 3;
        float acc[8];
        #pragma unroll
        for (int j = 0; j < 8; ++j) acc[j] = b[sub*8 + j];
        #pragma unroll
        for (int i = 0; i < PD; ++i) {
            float p = edge_props[(size_t)(e0 + e)*PD + i];
            #pragma unroll
            for (int j = 0; j < 8; ++j) acc[j] += p * W[i*KD + sub*8 + j];
        }
        #pragma unroll
        for (int j = 0; j < 8; ++j) ef[e*32 + sub*8 + j] = acc[j];
    }
    if (t < 64) {
        int e = e0 + t;
        int s = ei[e], d = ei[N_EDGES + e];
        float dx = positions[s*3+0] - positions[d*3+0];
        float dy = positions[s*3+1] - positions[d*3+1];
        float dz = positions[s*3+2] - positions[d*3+2];
        float rd = dx*dx + dy*dy + dz*dz;
        rdl[t] = rd;
        rel[e] = rd;
        atomicAdd(&deg[d], 1.f);
    }
    __syncthreads();

    int l = t & 63, w = t >> 6;
    int q = l >> 4, el = l & 15;
    float rd = rdl[16*w + el];
    #pragma unroll
    for (int kbr = 0; kbr < 3; ++kbr) {
        short8 out;
        #pragma unroll
        for (int i = 0; i < 8; ++i) {
            int k = 8*q + i;
            float v;
            if (kbr == 0)      v = sinf(ldexpf(rd, -k));
            else if (kbr == 1) v = cosf(ldexpf(rd, -k));
            else               v = ef[(16*w + el)*32 + k];
            out[i] = (short)f2bf(v);
        }
        *(short8*)&constpack[((((size_t)b0*4 + w)*3 + kbr)*64 + l)*8] = out;
    }
}

// ---------------- MFMA edge MLP (permuted W1, shuffle-free, fused GEMM2) ----------------
// 64 edges/block, 4 waves x 16 edges. No LDS, no barriers, NO cross-lane exchange:
// the W1p column permutation makes GEMM1 output land in GEMM2 A-frag layout directly.
__global__ __launch_bounds__(256) void edge_mlp_mfma(
    const unsigned short* __restrict__ feats_bf,
    const unsigned short* __restrict__ constpack,
    const float* __restrict__ rel, const int* __restrict__ ei,
    const unsigned short* __restrict__ W1p, const unsigned short* __restrict__ W2p,
    const float* __restrict__ w1rd, const float* __restrict__ eb1,
    const float* __restrict__ eb2, const float* __restrict__ lg,
    const float* __restrict__ lb, float* __restrict__ msum)
{
    int t = threadIdx.x;
    int b = blockIdx.x;
    int w = t >> 6, l = t & 63, q = l >> 4, el = l & 15;
    int e0 = b * 64;
    int eMine = e0 + 16*w + el;
    int srcn = ei[eMine];
    int dstn = ei[N_EDGES + eMine];
    float rd = rel[eMine];

    short8 a0 = *(const short8*)&feats_bf[(size_t)dstn*KD + 8*q];
    short8 a1 = *(const short8*)&feats_bf[(size_t)srcn*KD + 8*q];
    const unsigned short* cp = &constpack[((size_t)(b*4 + w)*3)*512 + (size_t)l*8];
    short8 a2 = *(const short8*)&cp[0];
    short8 a3 = *(const short8*)&cp[512];
    short8 a4 = *(const short8*)&cp[1024];

    f32x4 acc20 = {0.f, 0.f, 0.f, 0.f};
    f32x4 acc21 = {0.f, 0.f, 0.f, 0.f};
    unsigned pk0 = 0u, pk1 = 0u, pk2 = 0u, pk3 = 0u;

    #pragma unroll
    for (int nt = 0; nt < 21; ++nt) {
        // GEMM1 tile: two independent accumulator chains (3+2) for ILP
        f32x4 aA = {0.f, 0.f, 0.f, 0.f};
        f32x4 aB = {0.f, 0.f, 0.f, 0.f};
        const unsigned short* wb = &W1p[(size_t)(nt*5)*512 + (size_t)l*8];
        aA = __builtin_amdgcn_mfma_f32_16x16x32_bf16(*(const short8*)&wb[0],    a0, aA, 0, 0, 0);
        aA = __builtin_amdgcn_mfma_f32_16x16x32_bf16(*(const short8*)&wb[512],  a1, aA, 0, 0, 0);
        aA = __builtin_amdgcn_mfma_f32_16x16x32_bf16(*(const short8*)&wb[1024], a2, aA, 0, 0, 0);
        aB = __builtin_amdgcn_mfma_f32_16x16x32_bf16(*(const short8*)&wb[1536], a3, aB, 0, 0, 0);
        aB = __builtin_amdgcn_mfma_f32_16x16x32_bf16(*(const short8*)&wb[2048], a4, aB, 0, 0, 0);

        // permuted output index: lane holds original n1 = base + j
        int base = 32*(nt >> 1) + 4*(nt & 1) + 8*q;
        float vj[4];
        if (nt < 20) {
            f32x4 be = *(const f32x4*)&eb1[base];
            f32x4 wr = *(const f32x4*)&w1rd[base];
            #pragma unroll
            for (int j = 0; j < 4; ++j)
                vj[j] = silu_f(aA[j] + aB[j] + be[j] + rd * wr[j]);
        } else {
            #pragma unroll
            for (int j = 0; j < 4; ++j) {
                int n1 = base + j;
                bool ok = n1 < EIN2;
                float be = ok ? eb1[n1] : 0.f;
                float wr = ok ? w1rd[n1] : 0.f;
                float v = silu_f(aA[j] + aB[j] + be + rd * wr);
                vj[j] = ok ? v : 0.f;
            }
        }

        if ((nt & 1) == 0) {
            pk0 = cvt_pk_bf16(vj[0], vj[1]);
            pk1 = cvt_pk_bf16(vj[2], vj[3]);
        } else {
            pk2 = cvt_pk_bf16(vj[0], vj[1]);
            pk3 = cvt_pk_bf16(vj[2], vj[3]);
            const int kb2 = nt >> 1;
            u32x4 hv = { pk0, pk1, pk2, pk3 };
            short8 av = __builtin_bit_cast(short8, hv);
            short8 b0 = *(const short8*)&W2p[(size_t)kb2*512 + (size_t)l*8];
            short8 b1 = *(const short8*)&W2p[(size_t)(11 + kb2)*512 + (size_t)l*8];
            acc20 = __builtin_amdgcn_mfma_f32_16x16x32_bf16(av, b0, acc20, 0, 0, 0);
            acc21 = __builtin_amdgcn_mfma_f32_16x16x32_bf16(av, b1, acc21, 0, 0, 0);
        }
    }
    // final kb2 = 10: low half from nt=20, high half zero (k2 in [336,352))
    {
        u32x4 hv = { pk0, pk1, 0u, 0u };
        short8 av = __builtin_bit_cast(short8, hv);
        short8 b0 = *(const short8*)&W2p[(size_t)10*512 + (size_t)l*8];
        short8 b1 = *(const short8*)&W2p[(size_t)21*512 + (size_t)l*8];
        acc20 = __builtin_amdgcn_mfma_f32_16x16x32_bf16(av, b0, acc20, 0, 0, 0);
        acc21 = __builtin_amdgcn_mfma_f32_16x16x32_bf16(av, b1, acc21, 0, 0, 0);
    }

    // epilogue: silu -> per-edge LayerNorm (32 cols) -> atomic aggregate.
    // lane (q,el): edge 16w+4q+j (row), cols el and 16+el.
    i32x4 dstv = *(const i32x4*)&ei[N_EDGES + e0 + 16*w + 4*q];
    float e20 = eb2[el], e21 = eb2[16 + el];
    float g0v = lg[el],  g1v = lg[16 + el];
    float b0v = lb[el],  b1v = lb[16 + el];
    #pragma unroll
    for (int j = 0; j < 4; ++j) {
        float m0 = silu_f(acc20[j] + e20);
        float m1 = silu_f(acc21[j] + e21);
        float s = m0 + m1;
        s += __shfl_xor(s, 1, 16); s += __shfl_xor(s, 2, 16);
        s += __shfl_xor(s, 4, 16); s += __shfl_xor(s, 8, 16);
        float mu = s * (1.f/32.f);
        float d0 = m0 - mu, d1 = m1 - mu;
        float vv = d0*d0 + d1*d1;
        vv += __shfl_xor(vv, 1, 16); vv += __shfl_xor(vv, 2, 16);
        vv += __shfl_xor(vv, 4, 16); vv += __shfl_xor(vv, 8, 16);
        float rs = rsqrtf(vv * (1.f/32.f) + LN_EPS);
        int dst = dstv[j];
        atomicAdd(&msum[(size_t)dst*MD + el],      d0*rs*g0v + b0v);
        atomicAdd(&msum[(size_t)dst*MD + 16 + el], d1*rs*g1v + b1v);
    }
}

// ---------------- MFMA node MLP: 64 nodes/block, 16/wave, shuffle-free ----------------
__global__ __launch_bounds__(256) void node_mlp_mfma(
    const float* __restrict__ msum, const float* __restrict__ deg,
    const unsigned short* __restrict__ W1A, const unsigned short* __restrict__ W2A,
    const float* __restrict__ nb1, const float* __restrict__ nb2,
    const float* __restrict__ eln_g, const float* __restrict__ eln_b,
    const float* __restrict__ n1g, const float* __restrict__ n1b,
    const float* __restrict__ n2g, const float* __restrict__ n2b,
    float* __restrict__ feats, unsigned short* __restrict__ feats_bf,
    float* __restrict__ allf, int kslot)
{
    int t = threadIdx.x;
    int w = t >> 6, l = t & 63, q = l >> 4, el = l & 15;
    int nd = blockIdx.x*64 + 16*w + el;
    bool okn = nd < N_NODES;
    size_t ndc = okn ? (size_t)nd : (size_t)(N_NODES - 1);

    // ---- load input, dual group-LN, pack to B-frags ----
    float x[2][8];
    {
        f32x4 f0 = *(const f32x4*)&feats[ndc*KD + 8*q];
        f32x4 f1 = *(const f32x4*)&feats[ndc*KD + 8*q + 4];
        float inv = 1.f / fmaxf(deg[ndc], 1.f);
        f32x4 m0 = *(const f32x4*)&msum[ndc*KD + 8*q];
        f32x4 m1 = *(const f32x4*)&msum[ndc*KD + 8*q + 4];
        #pragma unroll
        for (int j = 0; j < 4; ++j) {
            x[0][j] = f0[j]; x[0][4+j] = f1[j];
            x[1][j] = m0[j]*inv; x[1][4+j] = m1[j]*inv;
        }
    }
    short8 xf[2];
    #pragma unroll
    for (int kb = 0; kb < 2; ++kb) {
        float s = 0.f;
        #pragma unroll
        for (int i = 0; i < 8; ++i) s += x[kb][i];
        s += __shfl_xor(s, 16); s += __shfl_xor(s, 32);
        float mu = s * (1.f/32.f);
        float vv = 0.f;
        #pragma unroll
        for (int i = 0; i < 8; ++i) { float d = x[kb][i] - mu; vv += d*d; }
        vv += __shfl_xor(vv, 16); vv += __shfl_xor(vv, 32);
        float rs = rsqrtf(vv * (1.f/32.f) + LN_EPS);
        const float* gp = kb ? eln_g : n1g;
        const float* bp = kb ? eln_b : n1b;
        f32x4 ga = *(const f32x4*)&gp[8*q];
        f32x4 gb = *(const f32x4*)&gp[8*q + 4];
        f32x4 ba = *(const f32x4*)&bp[8*q];
        f32x4 bb = *(const f32x4*)&bp[8*q + 4];
        float z[8];
        #pragma unroll
        for (int j = 0; j < 4; ++j) {
            z[j]   = (x[kb][j]   - mu)*rs*ga[j] + ba[j];
            z[4+j] = (x[kb][4+j] - mu)*rs*gb[j] + bb[j];
        }
        u32x4 pv = { cvt_pk_bf16(z[0], z[1]), cvt_pk_bf16(z[2], z[3]),
                     cvt_pk_bf16(z[4], z[5]), cvt_pk_bf16(z[6], z[7]) };
        xf[kb] = __builtin_bit_cast(short8, pv);
    }

    // ---- stage 1: h = silu(x @ W1 + b1), permuted W1A -> no exchange ----
    unsigned hr[8];
    #pragma unroll
    for (int mt = 0; mt < 4; ++mt) {
        f32x4 acc = {0.f, 0.f, 0.f, 0.f};
        acc = __builtin_amdgcn_mfma_f32_16x16x32_bf16(
            *(const short8*)&W1A[(size_t)(mt*2 + 0)*512 + (size_t)l*8], xf[0], acc, 0, 0, 0);
        acc = __builtin_amdgcn_mfma_f32_16x16x32_bf16(
            *(const short8*)&W1A[(size_t)(mt*2 + 1)*512 + (size_t)l*8], xf[1], acc, 0, 0, 0);
        int base = 32*(mt >> 1) + 4*(mt & 1) + 8*q;   // permuted output index
        f32x4 b1v = *(const f32x4*)&nb1[base];
        float vj[4];
        #pragma unroll
        for (int j = 0; j < 4; ++j) vj[j] = silu_f(acc[j] + b1v[j]);
        int ix = (mt >> 1)*4 + (mt & 1)*2;
        hr[ix]     = cvt_pk_bf16(vj[0], vj[1]);
        hr[ix + 1] = cvt_pk_bf16(vj[2], vj[3]);
    }

    // ---- stage 2: out = h @ W2 + b2 (swapped), then LN2 + residual ----
    u32x4 h0v = { hr[0], hr[1], hr[2], hr[3] };
    u32x4 h1v = { hr[4], hr[5], hr[6], hr[7] };
    short8 hf0 = __builtin_bit_cast(short8, h0v);
    short8 hf1 = __builtin_bit_cast(short8, h1v);
    float o[2][4];
    #pragma unroll
    for (int mt2 = 0; mt2 < 2; ++mt2) {
        f32x4 acc = {0.f, 0.f, 0.f, 0.f};
        acc = __builtin_amdgcn_mfma_f32_16x16x32_bf16(
            *(const short8*)&W2A[(size_t)(mt2*2 + 0)*512 + (size_t)l*8], hf0, acc, 0, 0, 0);
        acc = __builtin_amdgcn_mfma_f32_16x16x32_bf16(
            *(const short8*)&W2A[(size_t)(mt2*2 + 1)*512 + (size_t)l*8], hf1, acc, 0, 0, 0);
        f32x4 b2v = *(const f32x4*)&nb2[16*mt2 + 4*q];
        #pragma unroll
        for (int j = 0; j < 4; ++j) o[mt2][j] = acc[j] + b2v[j];
    }
    float s2 = 0.f;
    #pragma unroll
    for (int mt2 = 0; mt2 < 2; ++mt2)
        #pragma unroll
        for (int j = 0; j < 4; ++j) s2 += o[mt2][j];
    s2 += __shfl_xor(s2, 16); s2 += __shfl_xor(s2, 32);
    float mu2 = s2 * (1.f/32.f);
    float vv2 = 0.f;
    #pragma unroll
    for (int mt2 = 0; mt2 < 2; ++mt2)
        #pragma unroll
        for (int j = 0; j < 4; ++j) { float d = o[mt2][j] - mu2; vv2 += d*d; }
    vv2 += __shfl_xor(vv2, 16); vv2 += __shfl_xor(vv2, 32);
    float rs2 = rsqrtf(vv2 * (1.f/32.f) + LN_EPS);

    #pragma unroll
    for (int mt2 = 0; mt2 < 2; ++mt2) {
        f32x4 gv = *(const f32x4*)&n2g[16*mt2 + 4*q];
        f32x4 bv = *(const f32x4*)&n2b[16*mt2 + 4*q];
        f32x4 fold = *(const f32x4*)&feats[ndc*KD + 16*mt2 + 4*q];
        f32x4 nf;
        #pragma unroll
        for (int j = 0; j < 4; ++j)
            nf[j] = fold[j] + (o[mt2][j] - mu2)*rs2*gv[j] + bv[j];
        if (okn) {
            *(f32x4*)&feats[(size_t)nd*KD + 16*mt2 + 4*q] = nf;
            u32x2 pb = { cvt_pk_bf16(nf[0], nf[1]), cvt_pk_bf16(nf[2], nf[3]) };
            *(u32x2*)&feats_bf[(size_t)nd*KD + 16*mt2 + 4*q] = pb;
            *(f32x4*)&allf[(size_t)nd*ALLF + kslot*KD + 16*mt2 + 4*q] = nf;
        }
    }
}

// ---------------- mean pool: 4 blocks per graph, lane<->column ----------------
__global__ __launch_bounds__(256) void pool_kernel(
    const float* __restrict__ allf, const int* __restrict__ batch,
    float* __restrict__ gsum, float* __restrict__ gcnt)
{
    int b = blockIdx.x, t = threadIdx.x;
    int g = b >> 2, part = b & 3;
    int lo = 0, hi = N_NODES;
    while (lo < hi) { int m = (lo+hi) >> 1; if (batch[m] < g) lo = m+1; else hi = m; }
    int start = lo;
    hi = N_NODES;
    while (lo < hi) { int m = (lo+hi) >> 1; if (batch[m] < g+1) lo = m+1; else hi = m; }
    int end = lo;
    if (part == 0 && t == 0) gcnt[g] = (float)(end - start);
    int len = end - start;
    int chunk = (len + 3) >> 2;
    int s = start + part*chunk;
    int e = min(end, s + chunk);
    if (t < ALLF && e > s) {
        float acc = 0.f;
        for (int n = s; n < e; ++n) acc += allf[(size_t)n*ALLF + t];
        atomicAdd(&gsum[g*ALLF + t], acc);
    }
}

// ---------------- final FNN: block per graph ----------------
__global__ __launch_bounds__(256) void fnn_kernel(
    const float* __restrict__ gsum, const float* __restrict__ gcnt,
    const float* __restrict__ W0, const float* __restrict__ b0,
    const float* __restrict__ W1, const float* __restrict__ b1,
    const float* __restrict__ W2, const float* __restrict__ b2,
    const float* __restrict__ W3, const float* __restrict__ b3,
    float* __restrict__ out)
{
    __shared__ float xs[256];
    __shared__ float partial[4];
    int g = blockIdx.x, t = threadIdx.x;
    float inv = 1.f / fmaxf(gcnt[g], 1.f);
    if (t < ALLF) xs[t] = gsum[g*ALLF + t] * inv;
    __syncthreads();
    float acc = b0[t];
    for (int i = 0; i < ALLF; ++i) acc += xs[i] * W0[i*256 + t];
    acc = silu_f(acc);
    __syncthreads(); xs[t] = acc; __syncthreads();
    acc = b1[t];
    for (int i = 0; i < 256; ++i) acc += xs[i] * W1[i*256 + t];
    acc = silu_f(acc);
    __syncthreads(); xs[t] = acc; __syncthreads();
    acc = b2[t];
    for (int i = 0; i < 256; ++i) acc += xs[i] * W2[i*256 + t];
    acc = silu_f(acc);
    __syncthreads(); xs[t] = acc; __syncthreads();
    float v = xs[t] * W3[t];
    #pragma unroll
    for (int m = 32; m; m >>= 1) v += __shfl_xor(v, m, 64);
    if ((t & 63) == 0) partial[t >> 6] = v;
    __syncthreads();
    if (t == 0) out[g] = partial[0] + partial[1] + partial[2] + partial[3] + b3[0];
}

extern "C" void kernel_launch(void* const* d_in, const int* in_sizes, int n_in,
                              void* d_out, int out_size, void* d_ws, size_t ws_size,
                              hipStream_t stream) {
    const float* props      = (const float*)d_in[0];
    const float* positions  = (const float*)d_in[1];
    const float* edge_props = (const float*)d_in[2];
    const float* embed_W    = (const float*)d_in[3];
    const float* embed_b    = (const float*)d_in[4];
    const float* eeW        = (const float*)d_in[5];
    const float* eeb        = (const float*)d_in[6];
    const float* k_eW1      = (const float*)d_in[7];
    const float* k_eb1      = (const float*)d_in[8];
    const float* k_eW2      = (const float*)d_in[9];
    const float* k_eb2      = (const float*)d_in[10];
    const float* k_eln_g    = (const float*)d_in[11];
    const float* k_eln_b    = (const float*)d_in[12];
    const float* k_n1g      = (const float*)d_in[13];
    const float* k_n1b      = (const float*)d_in[14];
    const float* k_n2g      = (const float*)d_in[15];
    const float* k_n2b      = (const float*)d_in[16];
    const float* k_nW1      = (const float*)d_in[17];
    const float* k_nb1      = (const float*)d_in[18];
    const float* k_nW2      = (const float*)d_in[19];
    const float* k_nb2      = (const float*)d_in[20];
    const float* fnn_W0     = (const float*)d_in[21];
    const float* fnn_b0     = (const float*)d_in[22];
    const float* fnn_W1     = (const float*)d_in[23];
    const float* fnn_b1     = (const float*)d_in[24];
    const float* fnn_W2     = (const float*)d_in[25];
    const float* fnn_b2     = (const float*)d_in[26];
    const float* fnn_W3     = (const float*)d_in[27];
    const float* fnn_b3     = (const float*)d_in[28];
    const int*   ei         = (const int*)d_in[29];
    const int*   batch      = (const int*)d_in[30];
    float* out = (float*)d_out;

    // ---- workspace layout (bytes, 256-aligned) ----
    char* wsb = (char*)d_ws;
    size_t off = 0;
    #define WS_ALLOC(ptr_t, name, bytes) ptr_t name = (ptr_t)(wsb + off); off += (((size_t)(bytes)) + 255) & ~(size_t)255;
    WS_ALLOC(float*, feats, (size_t)N_NODES*KD*4)
    WS_ALLOC(float*, msum,  (size_t)N_NODES*KD*4)
    WS_ALLOC(float*, deg,   (size_t)N_NODES*4)
    WS_ALLOC(float*, rel,   (size_t)N_EDGES*4)
    WS_ALLOC(float*, gsum,  (size_t)N_GRAPHS*ALLF*4)
    WS_ALLOC(float*, gcnt,  (size_t)N_GRAPHS*4)
    WS_ALLOC(float*, allf,  (size_t)N_NODES*ALLF*4)
    WS_ALLOC(unsigned short*, feats_bf,  (size_t)N_NODES*KD*2)
    WS_ALLOC(unsigned short*, constpack, (size_t)5000*4*3*64*8*2)   // 61.44 MB
    WS_ALLOC(unsigned short*, W1p,  (size_t)NK*21*5*64*8*2)
    WS_ALLOC(unsigned short*, W2p,  (size_t)NK*2*11*64*8*2)
    WS_ALLOC(unsigned short*, W1An, (size_t)NK*4*2*64*8*2)
    WS_ALLOC(unsigned short*, W2An, (size_t)NK*2*2*64*8*2)
    (void)ws_size;

    hipMemsetAsync(deg,  0, (size_t)N_NODES*4, stream);
    hipMemsetAsync(gsum, 0, (size_t)N_GRAPHS*ALLF*4, stream);

    pack_w1_kernel<<<(NK*21*5*64 + 255)/256, 256, 0, stream>>>(k_eW1, W1p);
    pack_w2_kernel<<<(NK*2*11*64 + 255)/256, 256, 0, stream>>>(k_eW2, W2p);
    pack_nw_kernel<<<(NK*4*2*64 + NK*2*2*64 + 255)/256, 256, 0, stream>>>(k_nW1, k_nW2, W1An, W2An);
    embed_nodes_kernel<<<N_NODES/8, 256, 0, stream>>>(props, embed_W, embed_b,
                                                      feats, feats_bf, allf);
    edge_prep_kernel<<<N_EDGES/64, 256, 0, stream>>>(edge_props, positions, ei, eeW, eeb,
                                                     rel, deg, constpack);

    for (int k = 0; k < NK; ++k) {
        hipMemsetAsync(msum, 0, (size_t)N_NODES*KD*4, stream);
        edge_mlp_mfma<<<N_EDGES/64, 256, 0, stream>>>(
            feats_bf, constpack, rel, ei,
            W1p + (size_t)k*21*5*512, W2p + (size_t)k*2*11*512,
            k_eW1 + (size_t)k*EIN*EIN2 + 128*EIN2,
            k_eb1 + (size_t)k*EIN2, k_eb2 + (size_t)k*MD,
            k_eln_g + (size_t)k*MD, k_eln_b + (size_t)k*MD, msum);
        node_mlp_mfma<<<(N_NODES + 63)/64, 256, 0, stream>>>(
            msum, deg,
            W1An + (size_t)k*4*2*512, W2An + (size_t)k*2*2*512,
            k_nb1 + (size_t)k*64, k_nb2 + (size_t)k*32,
            k_eln_g + (size_t)k*MD, k_eln_b + (size_t)k*MD,
            k_n1g + (size_t)k*KD, k_n1b + (size_t)k*KD,
            k_n2g + (size_t)k*KD, k_n2b + (size_t)k*KD,
            feats, feats_bf, allf, k+1);
    }

    pool_kernel<<<N_GRAPHS*4, 256, 0, stream>>>(allf, batch, gsum, gcnt);
    fnn_kernel<<<N_GRAPHS, 256, 0, stream>>>(gsum, gcnt, fnn_W0, fnn_b0, fnn_W1, fnn_b1,
                                             fnn_W2, fnn_b2, fnn_W3, fnn_b3, out);
}